// Round 18
// baseline (1134.959 us; speedup 1.0000x reference)
//
#include <hip/hip_runtime.h>
#include <math.h>

#define B_ 8192
#define T_ 30
#define H_ 256
#define NG_ 1024
#define DT_ 0.03f
#define RB 16
#define NBLK (B_ / RB)   // 512 blocks -> 2 per CU

typedef __attribute__((ext_vector_type(8))) short short8;
typedef __attribute__((ext_vector_type(4))) float f32x4;
typedef __attribute__((ext_vector_type(4))) int i32x4;

__device__ inline float bf2f(unsigned short u) {
    unsigned int x = ((unsigned int)u) << 16;
    return __builtin_bit_cast(float, x);
}
__device__ inline unsigned short f2bf(float f) {
    unsigned int x = __builtin_bit_cast(unsigned int, f);
    return (unsigned short)((x + 0x7FFF + ((x >> 16) & 1)) >> 16);
}
__device__ inline float fast_tanh(float x) {
    float e = __expf(2.f * x);
    return 1.f - 2.f / (e + 1.f);
}
__device__ inline float fast_sigmoid(float x) {
    return 1.f / (1.f + __expf(-x));
}
__device__ inline void gl16(const signed char* g, signed char* l) {
    __builtin_amdgcn_global_load_lds((const __attribute__((address_space(1))) void*)g,
                                     (__attribute__((address_space(3))) void*)l, 16, 0, 0);
}

// ---------- fused fold+permute: WxP[r][n'] = (W1@W2)[r][co(n')], bfP[n'] = (b1@W2+bih+bhh)[co] ----------
// n' = bN*64 + g*16 + j  <->  co = g*256 + bN*16 + j
__global__ void fold_perm_kernel(const float* __restrict__ W1, const float* __restrict__ b1,
                                 const float* __restrict__ W2,
                                 const float* __restrict__ bih, const float* __restrict__ bhh,
                                 float* __restrict__ WxP, float* __restrict__ bfP) {
    __shared__ float sP[4][64];
    const int t63 = threadIdx.x & 63;
    const int kc = threadIdx.x >> 6;
    int o = blockIdx.x * 64 + t63;          // 0..5119 (r=4 is bias row)
    int r = o >> 10;
    int np = o & 1023;
    int bN = np >> 6, g = (np >> 4) & 3, j = np & 15;
    int co = g * 256 + bN * 16 + j;
    const float* w1row = (r < 4) ? (W1 + r * 128) : b1;
    float acc = 0.f;
    #pragma unroll 8
    for (int k = kc * 32; k < kc * 32 + 32; ++k)
        acc = fmaf(w1row[k], W2[k * NG_ + co], acc);
    sP[kc][t63] = acc;
    __syncthreads();
    if (kc == 0) {
        acc = sP[0][t63] + sP[1][t63] + sP[2][t63] + sP[3][t63];
        if (r < 4) WxP[r * NG_ + np] = acc;
        else       bfP[np] = acc + bih[co] + bhh[co];
    }
}

// INT8 packed weights (verified R11). Chunk-contiguous: chunk c = bytes [c*65536,(c+1)*65536).
// Within colgrp (16 gate-cols, 4096B): [k0(8)][kg(4)][fr(16)][e(8)].
__global__ void prep_pack_i8_kernel(const float* __restrict__ W, signed char* __restrict__ Wpk) {
    int id = blockIdx.x * blockDim.x + threadIdx.x;  // np*256 + k
    int np = id >> 8, k = id & 255;
    int bN = np >> 6, gg = (np >> 4) & 3, j = np & 15;
    int co = gg * 256 + bN * 16 + j;
    int colgrp = np >> 4, fr = np & 15;
    int k0 = k >> 5, kg = (k >> 3) & 3, e = k & 7;
    float q = rintf(W[(size_t)k * NG_ + co] * 2032.f);
    q = fminf(fmaxf(q, -127.f), 127.f);
    Wpk[colgrp * 4096 + k0 * 512 + kg * 128 + fr * 8 + e] = (signed char)q;
}

// WT[m][n][k] = bf16(W_m[k][n]) for 9 matrices (mu0..3, lv0..3, dec_init)
__global__ void prep_wt_all_kernel(const float* __restrict__ muW, const float* __restrict__ lvW,
                                   const float* __restrict__ diW, unsigned short* __restrict__ WT9) {
    int m = blockIdx.y;
    const float* src = (m < 4) ? muW + (size_t)m * 65536
                     : (m < 8) ? lvW + (size_t)(m - 4) * 65536
                               : diW;
    int id = blockIdx.x * 256 + threadIdx.x;
    int n = id >> 8, k = id & 255;
    WT9[(size_t)m * 65536 + id] = f2bf(src[k * H_ + n]);
}

// ---------- rel input + expert passthrough ----------
__global__ void rel_kernel(const float* __restrict__ traj, float* __restrict__ rel,
                           float4* __restrict__ expert) {
    int id = blockIdx.x * blockDim.x + threadIdx.x;
    if (id >= B_ * T_) return;
    int t = id % T_;
    const float* p = traj + (size_t)id * 4;
    float x = p[0], y = p[1];
    if (t > 0) { x -= p[-4]; y -= p[-3]; }
    float* o = rel + (size_t)id * 4;
    o[0] = x; o[1] = y; o[2] = p[2]; o[3] = p[3];
    expert[id] = ((const float4*)traj)[id];
}

// ---------- persistent LSTM v16: RB=16, 256 thr (4 waves), 2 blocks/CU, single buf+hL ----------
// Derivation from verified v15: rh deleted (16 rows = one MFMA A-tile), cq = wave 0..3.
// Single weight buffer: stage(c+1) issued after reads-done barrier; vmcnt(0) at chunk-ready.
// Single hL: all afr reads complete (lgkm-drained) before the first reads-done barrier,
// all h writes occur after it -> no ping-pong needed.
// LDS: buf 0..65536 | hL[16*264]i8 ..69760 | sL[64]f ..70016 | redL[128]f ..70528
#define SMEM16 70528

template <int DEC>
__global__ __launch_bounds__(256, 2) void lstm_persist16_kernel(
    const float* __restrict__ rel,            // enc: [B][T][4]
    const signed char* __restrict__ Wpk,      // int8 packed weights (chunk-contiguous)
    const float* __restrict__ WxP,            // [4][1024] permuted
    const float* __restrict__ bfP,            // [1024] permuted
    const float* __restrict__ cInit,          // dec: [B][256] f32
    const unsigned short* __restrict__ hInit, // dec: [B][256] bf16
    const float* __restrict__ initS,          // dec: [B][4]
    const float* __restrict__ Wc,             // dec: [256][2]
    const float* __restrict__ bc,             // dec: [2]
    unsigned short* __restrict__ hOut,        // enc: [B][256] bf16
    float* __restrict__ recons)               // dec: [B][T][4]
{
    extern __shared__ char smem[];
    signed char* buf = (signed char*)smem;                   // 64KB
    signed char* hL  = (signed char*)(smem + 65536);         // 16*264
    float* sLp  = (float*)(smem + 69760);
    float* redL = (float*)(smem + 70016);                    // [16 rows][4 cq][2]

    const int tid = threadIdx.x;
    const int lane = tid & 63;
    const int fr = lane & 15;
    const int kg = lane >> 4;
    const int cq = tid >> 6;          // wave 0..3: col-quarter of each 256-col chunk
    const int rowBase = blockIdx.x * RB;

    // ---- per-thread constants in registers (static-indexed; fixed for all steps) ----
    float wxR[4][4][4], bfR[4][4], wcR[4][2];
    float cReg[16];
    #pragma unroll
    for (int c = 0; c < 4; ++c) {
        const int np0 = c * 256 + cq * 64 + fr;
        const int u = (c * 4 + cq) * 16 + fr;
        #pragma unroll
        for (int g = 0; g < 4; ++g) bfR[c][g] = bfP[np0 + g * 16];
        #pragma unroll
        for (int k = 0; k < 4; ++k)
            #pragma unroll
            for (int g = 0; g < 4; ++g)
                wxR[c][k][g] = WxP[k * 1024 + np0 + g * 16];
        if (DEC) { wcR[c][0] = Wc[u * 2]; wcR[c][1] = Wc[u * 2 + 1]; }
        else     { wcR[c][0] = 0.f; wcR[c][1] = 0.f; }
        #pragma unroll
        for (int rr = 0; rr < 4; ++rr) {
            if (DEC) cReg[c * 4 + rr] =
                cInit[(size_t)(rowBase + kg * 4 + rr) * 256 + u];
            else cReg[c * 4 + rr] = 0.f;
        }
    }

    // ---- prologue LDS state ----
    {
        int row = tid >> 4, sb = tid & 15;     // 16 rows x 16 segs of 16 units
        signed char* dst = hL + row * 264 + sb * 16;
        if (DEC) {
            const unsigned short* src = hInit + (size_t)(rowBase + row) * 256 + sb * 16;
            #pragma unroll
            for (int i = 0; i < 16; ++i) {
                float h = bf2f(src[i]);
                h = fminf(fmaxf(h, -4.f), 4.f);
                dst[i] = (signed char)(int)rintf(h * 31.75f);   // scale 4/127
            }
        } else {
            *(long*)(dst) = 0L;
            *(long*)(dst + 8) = 0L;
        }
    }
    if (DEC) {
        if (tid < RB) *(float4*)(sLp + tid * 4) = *(const float4*)(initS + (size_t)(rowBase + tid) * 4);
    }
    float bc0 = 0.f, bc1 = 0.f;
    if (DEC && tid < RB) { bc0 = bc[0]; bc1 = bc[1]; }

    // cooperative lockstep staging: wave cq stages its 16KB of the 64KB chunk (16 x gl16)
    #define STAGE(ck)                                                               \
        {                                                                           \
            const signed char* gsrc = Wpk + (ck) * 65536 + cq * 16384 + lane * 16;  \
            signed char* ldst = buf + cq * 16384 + lane * 16;                       \
            _Pragma("unroll")                                                       \
            for (int q_ = 0; q_ < 16; ++q_) gl16(gsrc + q_ * 1024, ldst + q_ * 1024); \
        }

    STAGE(0);
    __syncthreads();   // prologue LDS (h, sL) visible; drains stage(0)

    for (int t = 0; t < T_; ++t) {
        const float dqA = (DEC && t == 0) ? (4.f / 258064.f) : (1.f / 258064.f);  // 2032*127

        long afr[8];
        float4 xv[4];
        float p0[4], p1[4];
        if (DEC) {
            #pragma unroll
            for (int i = 0; i < 4; ++i) { p0[i] = 0.f; p1[i] = 0.f; }
        }

        #pragma unroll
        for (int c = 0; c < 4; ++c) {
            // chunk-ready: this wave's stage of chunk c is the only outstanding vmem
            asm volatile("s_waitcnt vmcnt(0)" ::: "memory");
            asm volatile("s_waitcnt lgkmcnt(0)" ::: "memory");
            __builtin_amdgcn_s_barrier();   // chunk c in LDS; for c==0 also publishes prev h/sL
            __builtin_amdgcn_sched_barrier(0);

            if (c == 0) {
                // A-fragments (int8): rows fr, k-chunk kg (reads complete before reads-done bar)
                #pragma unroll
                for (int k0 = 0; k0 < 8; ++k0)
                    afr[k0] = *(const long*)(hL + fr * 264 + (k0 * 4 + kg) * 8);
                #pragma unroll
                for (int rr = 0; rr < 4; ++rr) {
                    int row = kg * 4 + rr;
                    if (DEC) xv[rr] = *(const float4*)(sLp + row * 4);
                    else     xv[rr] = *(const float4*)(rel + ((size_t)(rowBase + row) * T_ + t) * 4);
                }
            }

            i32x4 acc[4] = {};
            __builtin_amdgcn_s_setprio(1);
            #pragma unroll
            for (int k0 = 0; k0 < 8; ++k0) {
                long b0 = *(const long*)(buf + (cq * 4 + 0) * 4096 + k0 * 512 + lane * 8);
                long b1 = *(const long*)(buf + (cq * 4 + 1) * 4096 + k0 * 512 + lane * 8);
                long b2 = *(const long*)(buf + (cq * 4 + 2) * 4096 + k0 * 512 + lane * 8);
                long b3 = *(const long*)(buf + (cq * 4 + 3) * 4096 + k0 * 512 + lane * 8);
                acc[0] = __builtin_amdgcn_mfma_i32_16x16x32_i8(afr[k0], b0, acc[0], 0, 0, 0);
                acc[1] = __builtin_amdgcn_mfma_i32_16x16x32_i8(afr[k0], b1, acc[1], 0, 0, 0);
                acc[2] = __builtin_amdgcn_mfma_i32_16x16x32_i8(afr[k0], b2, acc[2], 0, 0, 0);
                acc[3] = __builtin_amdgcn_mfma_i32_16x16x32_i8(afr[k0], b3, acc[3], 0, 0, 0);
            }
            __builtin_amdgcn_s_setprio(0);
            asm volatile("s_waitcnt lgkmcnt(0)" ::: "memory");
            __builtin_amdgcn_sched_barrier(0);
            __builtin_amdgcn_s_barrier();   // reads of buf (and hL for c==0) done everywhere
            // refill the single buffer with the next chunk (c+1, or chunk 0 of next step)
            if (!(t == T_ - 1 && c == 3)) STAGE((c + 1) & 3);

            // epilogue: unit u = (c*4+cq)*16+fr; gates = acc[0..3]; rows kg*4+rr
            const int u = (c * 4 + cq) * 16 + fr;
            #pragma unroll
            for (int rr = 0; rr < 4; ++rr) {
                int row = kg * 4 + rr;
                float xk[4] = {xv[rr].x, xv[rr].y, xv[rr].z, xv[rr].w};
                float g0 = fmaf((float)acc[0][rr], dqA, bfR[c][0]);
                float g1 = fmaf((float)acc[1][rr], dqA, bfR[c][1]);
                float g2 = fmaf((float)acc[2][rr], dqA, bfR[c][2]);
                float g3 = fmaf((float)acc[3][rr], dqA, bfR[c][3]);
                #pragma unroll
                for (int k = 0; k < 4; ++k) {
                    g0 = fmaf(xk[k], wxR[c][k][0], g0);
                    g1 = fmaf(xk[k], wxR[c][k][1], g1);
                    g2 = fmaf(xk[k], wxR[c][k][2], g2);
                    g3 = fmaf(xk[k], wxR[c][k][3], g3);
                }
                float iv = fast_sigmoid(g0);
                float fv = fast_sigmoid(g1);
                float gv = fast_tanh(g2);
                float ov = fast_sigmoid(g3);
                float cn = fv * cReg[c * 4 + rr] + iv * gv;
                cReg[c * 4 + rr] = cn;
                float hval = ov * fast_tanh(cn);
                if (DEC) {
                    p0[rr] = fmaf(hval, wcR[c][0], p0[rr]);
                    p1[rr] = fmaf(hval, wcR[c][1], p1[rr]);
                }
                hL[row * 264 + u] = (signed char)(int)rintf(hval * 127.f);  // |h|<1
            }
        }

        if (DEC) {
            // each row receives partials from exactly 4 waves (cq)
            #pragma unroll
            for (int msk = 1; msk < 16; msk <<= 1)
                #pragma unroll
                for (int i = 0; i < 4; ++i) {
                    p0[i] += __shfl_xor(p0[i], msk);
                    p1[i] += __shfl_xor(p1[i], msk);
                }
            if (fr == 0) {
                #pragma unroll
                for (int rr = 0; rr < 4; ++rr) {
                    int row = kg * 4 + rr;
                    redL[(row * 4 + cq) * 2 + 0] = p0[rr];
                    redL[(row * 4 + cq) * 2 + 1] = p1[rr];
                }
            }
            asm volatile("s_waitcnt lgkmcnt(0)" ::: "memory");
            __builtin_amdgcn_s_barrier();
            if (tid < RB) {
                float q0 = 0.f, q1 = 0.f;
                #pragma unroll
                for (int p = 0; p < 4; ++p) {
                    q0 += redL[(tid * 4 + p) * 2 + 0];
                    q1 += redL[(tid * 4 + p) * 2 + 1];
                }
                float pedal = q0 + bc0;
                float steer = fminf(fmaxf(q1 + bc1, -0.5f), 0.5f);
                float4 sv = *(float4*)(sLp + tid * 4);
                float v = sv.w;
                float v1 = fminf(fmaxf(v + pedal * DT_, 0.f), 10.f);
                float pd = fminf(fmaxf(v * tanf(steer) * (1.f / 2.5f), -1.57f), 1.57f);
                float4 ns;
                ns.x = sv.x + v1 * cosf(sv.z) * DT_;
                ns.y = sv.y + v1 * sinf(sv.z) * DT_;
                ns.z = sv.z + pd * DT_;
                ns.w = v1;
                *(float4*)(sLp + tid * 4) = ns;
                *(float4*)(recons + ((size_t)(rowBase + tid) * T_ + t) * 4) = ns;
            }
        }
        // no step-end barrier: h/sL writes drained (lgkm) + published by chunk-0's barrier
    }

    if (!DEC) {   // final h -> bf16 global for MLPs
        asm volatile("s_waitcnt lgkmcnt(0)" ::: "memory");
        __builtin_amdgcn_s_barrier();
        int row = tid >> 4, sb = tid & 15;
        const signed char* src = hL + row * 264 + sb * 16;
        unsigned short hv[16];
        #pragma unroll
        for (int i = 0; i < 16; ++i)
            hv[i] = f2bf((float)src[i] * (1.f / 127.f));
        unsigned short* dst = hOut + (size_t)(rowBase + row) * 256 + sb * 16;
        *(short8*)(dst) = *(short8*)(hv);
        *(short8*)(dst + 8) = *(short8*)(hv + 8);
    }
    #undef STAGE
}

// ---------- MFMA GEMM for MLP layers (z-batched) ----------
__global__ __launch_bounds__(256) void mlp_gemm_kernel(
    const unsigned short* __restrict__ Ain, size_t aZStride,
    const unsigned short* __restrict__ WTb, size_t wZStride,
    const float* __restrict__ b0, const float* __restrict__ b1,
    float* __restrict__ outF, size_t ofZStride,
    unsigned short* __restrict__ outB, size_t obZStride,
    int act)
{
    const int z = blockIdx.z;
    const unsigned short* A  = Ain + (size_t)z * aZStride;
    const unsigned short* WT = WTb + (size_t)z * wZStride;
    const float* bias = z ? b1 : b0;

    __shared__ __align__(16) short sA[64 * 256];
    __shared__ __align__(16) short sBm[64 * 256];
    const int tid = threadIdx.x;
    const int lane = tid & 63;
    const int wr = (tid >> 7) & 1;
    const int wc = (tid >> 6) & 1;
    const int rowBase = blockIdx.x * 64;
    const int nBase = blockIdx.y * 64;

    {
        const unsigned short* gA = A + (size_t)rowBase * 256;
        const unsigned short* gB = WT + (size_t)nBase * 256;
        #pragma unroll
        for (int i = 0; i < 8; ++i) {
            int ch = tid + i * 256;
            int row = ch >> 5, slot = ch & 31;
            float4 va = *(const float4*)(gA + row * 256 + slot * 8);
            float4 vb = *(const float4*)(gB + row * 256 + slot * 8);
            int sl = slot ^ (row & 7);
            *(float4*)(sA + row * 256 + sl * 8) = va;
            *(float4*)(sBm + row * 256 + sl * 8) = vb;
        }
    }
    __syncthreads();

    const int fr = lane & 15;
    const int kg = lane >> 4;
    f32x4 acc[2][2] = {};
    #pragma unroll
    for (int k0 = 0; k0 < 8; ++k0) {
        int kch = k0 * 4 + kg;
        short8 a[2], b[2];
        #pragma unroll
        for (int m = 0; m < 2; ++m) {
            int r = wr * 32 + m * 16 + fr;
            a[m] = *(const short8*)(sA + r * 256 + (kch ^ (r & 7)) * 8);
        }
        #pragma unroll
        for (int n = 0; n < 2; ++n) {
            int r = wc * 32 + n * 16 + fr;
            b[n] = *(const short8*)(sBm + r * 256 + (kch ^ (r & 7)) * 8);
        }
        #pragma unroll
        for (int m = 0; m < 2; ++m)
            #pragma unroll
            for (int n = 0; n < 2; ++n)
                acc[m][n] = __builtin_amdgcn_mfma_f32_16x16x32_bf16(a[m], b[n], acc[m][n], 0, 0, 0);
    }

    #pragma unroll
    for (int m = 0; m < 2; ++m) {
        #pragma unroll
        for (int n = 0; n < 2; ++n) {
            int col = nBase + wc * 32 + n * 16 + fr;
            float bv = bias[col];
            #pragma unroll
            for (int r = 0; r < 4; ++r) {
                int row = rowBase + wr * 32 + m * 16 + kg * 4 + r;
                float v = acc[m][n][r] + bv;
                if (act) v = v > 0.f ? v : 0.01f * v;
                if (outF) outF[(size_t)z * ofZStride + (size_t)row * H_ + col] = v;
                if (outB) outB[(size_t)z * obZStride + (size_t)row * H_ + col] = f2bf(v);
            }
        }
    }
}

// ---------- z = tanh(eps*exp(0.5*lv)+mu) -> bf16 ----------
__global__ void z_kernel(const float* __restrict__ eps, const float* __restrict__ mu,
                         const float* __restrict__ lv, unsigned short* __restrict__ z) {
    int id = blockIdx.x * blockDim.x + threadIdx.x;
    z[id] = f2bf(tanhf(eps[id] * expf(0.5f * lv[id]) + mu[id]));
}

extern "C" void kernel_launch(void* const* d_in, const int* in_sizes, int n_in,
                              void* d_out, int out_size, void* d_ws, size_t ws_size,
                              hipStream_t stream) {
    (void)in_sizes; (void)n_in; (void)out_size; (void)ws_size;
    const float* traj       = (const float*)d_in[0];
    const float* init_s     = (const float*)d_in[1];
    const float* eps        = (const float*)d_in[2];
    const float* enc_emb_W  = (const float*)d_in[3];
    const float* enc_emb_b  = (const float*)d_in[4];
    const float* enc_Wih    = (const float*)d_in[5];
    const float* enc_bih    = (const float*)d_in[6];
    const float* enc_Whh    = (const float*)d_in[7];
    const float* enc_bhh    = (const float*)d_in[8];
    const float* mu_W       = (const float*)d_in[9];
    const float* mu_b       = (const float*)d_in[10];
    const float* lv_W       = (const float*)d_in[11];
    const float* lv_b       = (const float*)d_in[12];
    const float* dec_emb_W  = (const float*)d_in[13];
    const float* dec_emb_b  = (const float*)d_in[14];
    const float* dec_init_W = (const float*)d_in[15];
    const float* dec_init_b = (const float*)d_in[16];
    const float* dec_Wih    = (const float*)d_in[17];
    const float* dec_bih    = (const float*)d_in[18];
    const float* dec_Whh    = (const float*)d_in[19];
    const float* dec_bhh    = (const float*)d_in[20];
    const float* ctrl_W     = (const float*)d_in[21];
    const float* ctrl_b     = (const float*)d_in[22];

    float* out = (float*)d_out;
    float* recons = out;                              // B*T*4
    float* expert = out + (size_t)B_ * T_ * 4;        // B*T*4
    float* mu_out = expert + (size_t)B_ * T_ * 4;     // B*H
    float* lv_out = mu_out + (size_t)B_ * H_;         // B*H

    float* ws = (float*)d_ws;
    size_t o = 0;
    float* rel = ws + o;  o += (size_t)B_ * T_ * 4;
    signed char* WpkE = (signed char*)(ws + o); o += NG_ * H_ / 4;     // int8 image (256KB)
    signed char* WpkD = (signed char*)(ws + o); o += NG_ * H_ / 4;
    unsigned short* WT9  = (unsigned short*)(ws + o); o += 9 * H_ * H_ / 2;
    float* WxPE = ws + o; o += 4 * NG_;
    float* WxPD = ws + o; o += 4 * NG_;
    float* bfPE = ws + o; o += NG_;
    float* bfPD = ws + o; o += NG_;
    unsigned short* hEnc = (unsigned short*)(ws + o); o += (size_t)B_ * H_ / 2;
    unsigned short* tbA  = (unsigned short*)(ws + o); o += (size_t)B_ * H_;  // 2 z-slots
    unsigned short* tbB  = (unsigned short*)(ws + o); o += (size_t)B_ * H_;  // 2 z-slots
    float* cInit = ws + o; o += (size_t)B_ * H_;
    unsigned short* hInit = (unsigned short*)(ws + o); o += (size_t)B_ * H_ / 2;

    hipFuncSetAttribute((const void*)lstm_persist16_kernel<0>,
                        hipFuncAttributeMaxDynamicSharedMemorySize, SMEM16);
    hipFuncSetAttribute((const void*)lstm_persist16_kernel<1>,
                        hipFuncAttributeMaxDynamicSharedMemorySize, SMEM16);

    // ---- prep ----
    fold_perm_kernel<<<80, 256, 0, stream>>>(enc_emb_W, enc_emb_b, enc_Wih, enc_bih, enc_bhh, WxPE, bfPE);
    fold_perm_kernel<<<80, 256, 0, stream>>>(dec_emb_W, dec_emb_b, dec_Wih, dec_bih, dec_bhh, WxPD, bfPD);
    prep_pack_i8_kernel<<<1024, 256, 0, stream>>>(enc_Whh, WpkE);
    prep_pack_i8_kernel<<<1024, 256, 0, stream>>>(dec_Whh, WpkD);
    prep_wt_all_kernel<<<dim3(256, 9), 256, 0, stream>>>(mu_W, lv_W, dec_init_W, WT9);
    rel_kernel<<<(B_ * T_ + 255) / 256, 256, 0, stream>>>(traj, rel, (float4*)expert);

    // ---- encoder (one persistent launch, 2 blocks/CU) ----
    lstm_persist16_kernel<0><<<NBLK, 256, SMEM16, stream>>>(
        rel, WpkE, WxPE, bfPE, nullptr, nullptr, nullptr, nullptr, nullptr, hEnc, nullptr);

    // ---- mu/lv MLPs, z-batched ----
    dim3 gridM2(B_ / 64, H_ / 64, 2);
    size_t BH = (size_t)B_ * H_;
    mlp_gemm_kernel<<<gridM2, 256, 0, stream>>>(hEnc, 0, WT9 + 0 * 65536, (size_t)4 * 65536,
                                                mu_b + 0,   lv_b + 0,   nullptr, 0, tbA, BH, 1);
    mlp_gemm_kernel<<<gridM2, 256, 0, stream>>>(tbA, BH, WT9 + 1 * 65536, (size_t)4 * 65536,
                                                mu_b + 256, lv_b + 256, nullptr, 0, tbB, BH, 1);
    mlp_gemm_kernel<<<gridM2, 256, 0, stream>>>(tbB, BH, WT9 + 2 * 65536, (size_t)4 * 65536,
                                                mu_b + 512, lv_b + 512, nullptr, 0, tbA, BH, 1);
    mlp_gemm_kernel<<<gridM2, 256, 0, stream>>>(tbA, BH, WT9 + 3 * 65536, (size_t)4 * 65536,
                                                mu_b + 768, lv_b + 768, mu_out, BH, nullptr, 0, 1);

    // ---- z, decoder init ----
    z_kernel<<<B_ * H_ / 256, 256, 0, stream>>>(eps, mu_out, lv_out, tbB);
    dim3 gridM1(B_ / 64, H_ / 64, 1);
    mlp_gemm_kernel<<<gridM1, 256, 0, stream>>>(tbB, 0, WT9 + 8 * 65536, 0,
                                                dec_init_b, dec_init_b, cInit, 0, hInit, 0, 0);

    // ---- decoder (one persistent launch, 2 blocks/CU) ----
    lstm_persist16_kernel<1><<<NBLK, 256, SMEM16, stream>>>(
        nullptr, WpkD, WxPD, bfPD, cInit, hInit, init_s, ctrl_W, ctrl_b, nullptr, recons);
}

// Round 19
// 767.649 us; speedup vs baseline: 1.4785x; 1.4785x over previous
//
#include <hip/hip_runtime.h>
#include <math.h>

#define B_ 8192
#define T_ 30
#define H_ 256
#define NG_ 1024
#define DT_ 0.03f
#define RB 32
#define NBLK (B_ / RB)   // 256

typedef __attribute__((ext_vector_type(8))) short short8;
typedef __attribute__((ext_vector_type(4))) float f32x4;
typedef __attribute__((ext_vector_type(4))) int i32x4;

__device__ inline float bf2f(unsigned short u) {
    unsigned int x = ((unsigned int)u) << 16;
    return __builtin_bit_cast(float, x);
}
__device__ inline unsigned short f2bf(float f) {
    unsigned int x = __builtin_bit_cast(unsigned int, f);
    return (unsigned short)((x + 0x7FFF + ((x >> 16) & 1)) >> 16);
}
__device__ inline float fast_tanh(float x) {
    float e = __expf(2.f * x);
    return 1.f - 2.f / (e + 1.f);
}
__device__ inline float fast_sigmoid(float x) {
    return 1.f / (1.f + __expf(-x));
}
__device__ inline void gl16(const signed char* g, signed char* l) {
    __builtin_amdgcn_global_load_lds((const __attribute__((address_space(1))) void*)g,
                                     (__attribute__((address_space(3))) void*)l, 16, 0, 0);
}

// ---------- fused fold+permute: WxP[r][n'] = (W1@W2)[r][co(n')], bfP[n'] = (b1@W2+bih+bhh)[co] ----------
// n' = bN*64 + g*16 + j  <->  co = g*256 + bN*16 + j
__global__ void fold_perm_kernel(const float* __restrict__ W1, const float* __restrict__ b1,
                                 const float* __restrict__ W2,
                                 const float* __restrict__ bih, const float* __restrict__ bhh,
                                 float* __restrict__ WxP, float* __restrict__ bfP) {
    __shared__ float sP[4][64];
    const int t63 = threadIdx.x & 63;
    const int kc = threadIdx.x >> 6;
    int o = blockIdx.x * 64 + t63;          // 0..5119 (r=4 is bias row)
    int r = o >> 10;
    int np = o & 1023;
    int bN = np >> 6, g = (np >> 4) & 3, j = np & 15;
    int co = g * 256 + bN * 16 + j;
    const float* w1row = (r < 4) ? (W1 + r * 128) : b1;
    float acc = 0.f;
    #pragma unroll 8
    for (int k = kc * 32; k < kc * 32 + 32; ++k)
        acc = fmaf(w1row[k], W2[k * NG_ + co], acc);
    sP[kc][t63] = acc;
    __syncthreads();
    if (kc == 0) {
        acc = sP[0][t63] + sP[1][t63] + sP[2][t63] + sP[3][t63];
        if (r < 4) WxP[r * NG_ + np] = acc;
        else       bfP[np] = acc + bih[co] + bhh[co];
    }
}

// INT8 packed weights (verified R11). Chunk-contiguous: chunk c = bytes [c*65536,(c+1)*65536).
// Within colgrp (16 gate-cols, 4096B): [k0(8)][kg(4)][fr(16)][e(8)].
__global__ void prep_pack_i8_kernel(const float* __restrict__ W, signed char* __restrict__ Wpk) {
    int id = blockIdx.x * blockDim.x + threadIdx.x;  // np*256 + k
    int np = id >> 8, k = id & 255;
    int bN = np >> 6, gg = (np >> 4) & 3, j = np & 15;
    int co = gg * 256 + bN * 16 + j;
    int colgrp = np >> 4, fr = np & 15;
    int k0 = k >> 5, kg = (k >> 3) & 3, e = k & 7;
    float q = rintf(W[(size_t)k * NG_ + co] * 2032.f);
    q = fminf(fmaxf(q, -127.f), 127.f);
    Wpk[colgrp * 4096 + k0 * 512 + kg * 128 + fr * 8 + e] = (signed char)q;
}

// WT[m][n][k] = bf16(W_m[k][n]) for 9 matrices (mu0..3, lv0..3, dec_init)
__global__ void prep_wt_all_kernel(const float* __restrict__ muW, const float* __restrict__ lvW,
                                   const float* __restrict__ diW, unsigned short* __restrict__ WT9) {
    int m = blockIdx.y;
    const float* src = (m < 4) ? muW + (size_t)m * 65536
                     : (m < 8) ? lvW + (size_t)(m - 4) * 65536
                               : diW;
    int id = blockIdx.x * 256 + threadIdx.x;
    int n = id >> 8, k = id & 255;
    WT9[(size_t)m * 65536 + id] = f2bf(src[k * H_ + n]);
}

// ---------- rel input + expert passthrough ----------
__global__ void rel_kernel(const float* __restrict__ traj, float* __restrict__ rel,
                           float4* __restrict__ expert) {
    int id = blockIdx.x * blockDim.x + threadIdx.x;
    if (id >= B_ * T_) return;
    int t = id % T_;
    const float* p = traj + (size_t)id * 4;
    float x = p[0], y = p[1];
    if (t > 0) { x -= p[-4]; y -= p[-3]; }
    float* o = rel + (size_t)id * 4;
    o[0] = x; o[1] = y; o[2] = p[2]; o[3] = p[3];
    expert[id] = ((const float4*)traj)[id];
}

// ---------- persistent LSTM v15: lockstep dbuf gl_lds staging (L2-resident), merged barriers ----------
// LDS: buf0 0..65536 | buf1 ..131072 | hBuf[2][32*264]i8 ..147968 | sL[128]f ..148480 | redL ..150528
#define SMEM15 150528

template <int DEC>
__global__ __launch_bounds__(512, 2) void lstm_persist15_kernel(
    const float* __restrict__ rel,            // enc: [B][T][4]
    const signed char* __restrict__ Wpk,      // int8 packed weights (chunk-contiguous)
    const float* __restrict__ WxP,            // [4][1024] permuted
    const float* __restrict__ bfP,            // [1024] permuted
    const float* __restrict__ cInit,          // dec: [B][256] f32
    const unsigned short* __restrict__ hInit, // dec: [B][256] bf16
    const float* __restrict__ initS,          // dec: [B][4]
    const float* __restrict__ Wc,             // dec: [256][2]
    const float* __restrict__ bc,             // dec: [2]
    unsigned short* __restrict__ hOut,        // enc: [B][256] bf16
    float* __restrict__ recons)               // dec: [B][T][4]
{
    extern __shared__ char smem[];
    signed char* bufs = (signed char*)smem;                  // 2 x 64KB
    signed char* hL   = (signed char*)(smem + 131072);       // 2 x 8448
    float* sLp  = (float*)(smem + 147968);
    float* redL = (float*)(smem + 148480);                   // [32 rows][4 cq][2] floats

    const int tid = threadIdx.x;
    const int lane = tid & 63;
    const int fr = lane & 15;
    const int kg = lane >> 4;
    const int w = tid >> 6;
    const int rh = w >> 2;            // row-half (16 rows)
    const int cq = w & 3;             // col-quarter within each 256-col chunk
    const int rowBase = blockIdx.x * RB;

    // ---- per-thread constants in registers (static-indexed; fixed for all steps) ----
    float wxR[4][4][4], bfR[4][4], wcR[4][2];
    float cReg[16];
    #pragma unroll
    for (int c = 0; c < 4; ++c) {
        const int np0 = c * 256 + cq * 64 + fr;
        const int u = (c * 4 + cq) * 16 + fr;
        #pragma unroll
        for (int g = 0; g < 4; ++g) bfR[c][g] = bfP[np0 + g * 16];
        #pragma unroll
        for (int k = 0; k < 4; ++k)
            #pragma unroll
            for (int g = 0; g < 4; ++g)
                wxR[c][k][g] = WxP[k * 1024 + np0 + g * 16];
        if (DEC) { wcR[c][0] = Wc[u * 2]; wcR[c][1] = Wc[u * 2 + 1]; }
        else     { wcR[c][0] = 0.f; wcR[c][1] = 0.f; }
        #pragma unroll
        for (int rr = 0; rr < 4; ++rr) {
            if (DEC) cReg[c * 4 + rr] =
                cInit[(size_t)(rowBase + rh * 16 + kg * 4 + rr) * 256 + u];
            else cReg[c * 4 + rr] = 0.f;
        }
    }

    // ---- prologue LDS state ----
    {
        int row = tid >> 4, sb = tid & 15;     // 32 rows x 16 segs of 16 units
        signed char* dst = hL + row * 264 + sb * 16;
        if (DEC) {
            const unsigned short* src = hInit + (size_t)(rowBase + row) * 256 + sb * 16;
            #pragma unroll
            for (int i = 0; i < 16; ++i) {
                float h = bf2f(src[i]);
                h = fminf(fmaxf(h, -4.f), 4.f);
                dst[i] = (signed char)(int)rintf(h * 31.75f);   // scale 4/127
            }
        } else {
            *(long*)(dst) = 0L;
            *(long*)(dst + 8) = 0L;
        }
    }
    if (DEC) {
        if (tid < RB) *(float4*)(sLp + tid * 4) = *(const float4*)(initS + (size_t)(rowBase + tid) * 4);
    }
    float bc0 = 0.f, bc1 = 0.f;
    if (DEC && tid < RB) { bc0 = bc[0]; bc1 = bc[1]; }

    // cooperative lockstep staging: wave w stages its 8KB of each 64KB chunk (8 x gl16)
    #define STAGE(ck, bp)                                                          \
        {                                                                          \
            const signed char* gsrc = Wpk + (ck) * 65536 + w * 8192 + lane * 16;   \
            signed char* ldst = bufs + (bp) * 65536 + w * 8192 + lane * 16;        \
            _Pragma("unroll")                                                      \
            for (int q_ = 0; q_ < 8; ++q_) gl16(gsrc + q_ * 1024, ldst + q_ * 1024); \
        }

    STAGE(0, 0);
    STAGE(1, 1);
    __syncthreads();   // prologue LDS (h, sL) visible; drains prologue stages

    for (int t = 0; t < T_; ++t) {
        signed char* rbuf = hL + (t & 1) * 8448;
        signed char* wbuf = hL + ((t + 1) & 1) * 8448;
        const float dqA = (DEC && t == 0) ? (4.f / 258064.f) : (1.f / 258064.f);  // 2032*127

        long afr[8];
        float4 xv[4];
        float p0[4], p1[4];
        if (DEC) {
            #pragma unroll
            for (int i = 0; i < 4; ++i) { p0[i] = 0.f; p1[i] = 0.f; }
        }

        #pragma unroll
        for (int c = 0; c < 4; ++c) {
            signed char* bufc = bufs + (c & 1) * 65536;
            // steady state: vmcnt(8) drains chunk-c's stage (in-order retirement; xv vmem
            // ops sit older in the queue and are drained too). Tail needs full drain.
            if (t == T_ - 1 && c == 3) asm volatile("s_waitcnt vmcnt(0)" ::: "memory");
            else                       asm volatile("s_waitcnt vmcnt(8)" ::: "memory");
            asm volatile("s_waitcnt lgkmcnt(0)" ::: "memory");
            __builtin_amdgcn_s_barrier();   // chunk ready; for c==0 also: prev step's h/sL writes visible
            __builtin_amdgcn_sched_barrier(0);

            if (c == 0) {
                // A-fragments (int8): rows rh*16+fr, k-chunk kg  (rbuf != wbuf: no conflict)
                #pragma unroll
                for (int k0 = 0; k0 < 8; ++k0)
                    afr[k0] = *(const long*)(rbuf + (rh * 16 + fr) * 264 + (k0 * 4 + kg) * 8);
                // x vectors (rows rh*16+kg*4+rr)
                #pragma unroll
                for (int rr = 0; rr < 4; ++rr) {
                    int row = rh * 16 + kg * 4 + rr;
                    if (DEC) xv[rr] = *(const float4*)(sLp + row * 4);
                    else     xv[rr] = *(const float4*)(rel + ((size_t)(rowBase + row) * T_ + t) * 4);
                }
            }

            i32x4 acc[4] = {};
            __builtin_amdgcn_s_setprio(1);
            #pragma unroll
            for (int k0 = 0; k0 < 8; ++k0) {
                long b0 = *(const long*)(bufc + (cq * 4 + 0) * 4096 + k0 * 512 + lane * 8);
                long b1 = *(const long*)(bufc + (cq * 4 + 1) * 4096 + k0 * 512 + lane * 8);
                long b2 = *(const long*)(bufc + (cq * 4 + 2) * 4096 + k0 * 512 + lane * 8);
                long b3 = *(const long*)(bufc + (cq * 4 + 3) * 4096 + k0 * 512 + lane * 8);
                acc[0] = __builtin_amdgcn_mfma_i32_16x16x32_i8(afr[k0], b0, acc[0], 0, 0, 0);
                acc[1] = __builtin_amdgcn_mfma_i32_16x16x32_i8(afr[k0], b1, acc[1], 0, 0, 0);
                acc[2] = __builtin_amdgcn_mfma_i32_16x16x32_i8(afr[k0], b2, acc[2], 0, 0, 0);
                acc[3] = __builtin_amdgcn_mfma_i32_16x16x32_i8(afr[k0], b3, acc[3], 0, 0, 0);
            }
            __builtin_amdgcn_s_setprio(0);
            asm volatile("s_waitcnt lgkmcnt(0)" ::: "memory");
            __builtin_amdgcn_sched_barrier(0);
            __builtin_amdgcn_s_barrier();   // all waves' reads of bufc done -> safe to overwrite
            if (!(t == T_ - 1 && c >= 2)) STAGE((c + 2) & 3, (c & 1));

            // epilogue: unit u = (c*4+cq)*16+fr; gates = acc[0..3]; rows rh*16+kg*4+rr
            const int u = (c * 4 + cq) * 16 + fr;
            #pragma unroll
            for (int rr = 0; rr < 4; ++rr) {
                int row = rh * 16 + kg * 4 + rr;
                float xk[4] = {xv[rr].x, xv[rr].y, xv[rr].z, xv[rr].w};
                float g0 = fmaf((float)acc[0][rr], dqA, bfR[c][0]);
                float g1 = fmaf((float)acc[1][rr], dqA, bfR[c][1]);
                float g2 = fmaf((float)acc[2][rr], dqA, bfR[c][2]);
                float g3 = fmaf((float)acc[3][rr], dqA, bfR[c][3]);
                #pragma unroll
                for (int k = 0; k < 4; ++k) {
                    g0 = fmaf(xk[k], wxR[c][k][0], g0);
                    g1 = fmaf(xk[k], wxR[c][k][1], g1);
                    g2 = fmaf(xk[k], wxR[c][k][2], g2);
                    g3 = fmaf(xk[k], wxR[c][k][3], g3);
                }
                float iv = fast_sigmoid(g0);
                float fv = fast_sigmoid(g1);
                float gv = fast_tanh(g2);
                float ov = fast_sigmoid(g3);
                float cn = fv * cReg[c * 4 + rr] + iv * gv;
                cReg[c * 4 + rr] = cn;
                float hval = ov * fast_tanh(cn);
                if (DEC) {
                    p0[rr] = fmaf(hval, wcR[c][0], p0[rr]);
                    p1[rr] = fmaf(hval, wcR[c][1], p1[rr]);
                }
                wbuf[row * 264 + u] = (signed char)(int)rintf(hval * 127.f);  // |h|<1
            }
        }

        if (DEC) {
            // each row receives partials from exactly 4 waves (its rh-half): index by cq
            #pragma unroll
            for (int msk = 1; msk < 16; msk <<= 1)
                #pragma unroll
                for (int i = 0; i < 4; ++i) {
                    p0[i] += __shfl_xor(p0[i], msk);
                    p1[i] += __shfl_xor(p1[i], msk);
                }
            if (fr == 0) {
                #pragma unroll
                for (int rr = 0; rr < 4; ++rr) {
                    int row = rh * 16 + kg * 4 + rr;
                    redL[(row * 4 + cq) * 2 + 0] = p0[rr];
                    redL[(row * 4 + cq) * 2 + 1] = p1[rr];
                }
            }
            asm volatile("s_waitcnt lgkmcnt(0)" ::: "memory");
            __builtin_amdgcn_s_barrier();
            if (tid < RB) {
                float q0 = 0.f, q1 = 0.f;
                #pragma unroll
                for (int p = 0; p < 4; ++p) {
                    q0 += redL[(tid * 4 + p) * 2 + 0];
                    q1 += redL[(tid * 4 + p) * 2 + 1];
                }
                float pedal = q0 + bc0;
                float steer = fminf(fmaxf(q1 + bc1, -0.5f), 0.5f);
                float4 sv = *(float4*)(sLp + tid * 4);
                float v = sv.w;
                float v1 = fminf(fmaxf(v + pedal * DT_, 0.f), 10.f);
                float pd = fminf(fmaxf(v * tanf(steer) * (1.f / 2.5f), -1.57f), 1.57f);
                float4 ns;
                ns.x = sv.x + v1 * cosf(sv.z) * DT_;
                ns.y = sv.y + v1 * sinf(sv.z) * DT_;
                ns.z = sv.z + pd * DT_;
                ns.w = v1;
                *(float4*)(sLp + tid * 4) = ns;
                *(float4*)(recons + ((size_t)(rowBase + tid) * T_ + t) * 4) = ns;
            }
        }
        // no step-end barrier: h/sL writes are drained (lgkm) + published by chunk-0's
        // barrier of the next step; afr/xv reads moved after that barrier.
    }

    if (!DEC) {   // final h (hBuf[T&1]) -> bf16 global for MLPs
        asm volatile("s_waitcnt lgkmcnt(0)" ::: "memory");
        __builtin_amdgcn_s_barrier();
        int row = tid >> 4, sb = tid & 15;
        const signed char* src = hL + (T_ & 1) * 8448 + row * 264 + sb * 16;
        unsigned short hv[16];
        #pragma unroll
        for (int i = 0; i < 16; ++i)
            hv[i] = f2bf((float)src[i] * (1.f / 127.f));
        unsigned short* dst = hOut + (size_t)(rowBase + row) * 256 + sb * 16;
        *(short8*)(dst) = *(short8*)(hv);
        *(short8*)(dst + 8) = *(short8*)(hv + 8);
    }
    #undef STAGE
}

// ---------- MFMA GEMM for MLP layers (z-batched) ----------
__global__ __launch_bounds__(256) void mlp_gemm_kernel(
    const unsigned short* __restrict__ Ain, size_t aZStride,
    const unsigned short* __restrict__ WTb, size_t wZStride,
    const float* __restrict__ b0, const float* __restrict__ b1,
    float* __restrict__ outF, size_t ofZStride,
    unsigned short* __restrict__ outB, size_t obZStride,
    int act)
{
    const int z = blockIdx.z;
    const unsigned short* A  = Ain + (size_t)z * aZStride;
    const unsigned short* WT = WTb + (size_t)z * wZStride;
    const float* bias = z ? b1 : b0;

    __shared__ __align__(16) short sA[64 * 256];
    __shared__ __align__(16) short sBm[64 * 256];
    const int tid = threadIdx.x;
    const int lane = tid & 63;
    const int wr = (tid >> 7) & 1;
    const int wc = (tid >> 6) & 1;
    const int rowBase = blockIdx.x * 64;
    const int nBase = blockIdx.y * 64;

    {
        const unsigned short* gA = A + (size_t)rowBase * 256;
        const unsigned short* gB = WT + (size_t)nBase * 256;
        #pragma unroll
        for (int i = 0; i < 8; ++i) {
            int ch = tid + i * 256;
            int row = ch >> 5, slot = ch & 31;
            float4 va = *(const float4*)(gA + row * 256 + slot * 8);
            float4 vb = *(const float4*)(gB + row * 256 + slot * 8);
            int sl = slot ^ (row & 7);
            *(float4*)(sA + row * 256 + sl * 8) = va;
            *(float4*)(sBm + row * 256 + sl * 8) = vb;
        }
    }
    __syncthreads();

    const int fr = lane & 15;
    const int kg = lane >> 4;
    f32x4 acc[2][2] = {};
    #pragma unroll
    for (int k0 = 0; k0 < 8; ++k0) {
        int kch = k0 * 4 + kg;
        short8 a[2], b[2];
        #pragma unroll
        for (int m = 0; m < 2; ++m) {
            int r = wr * 32 + m * 16 + fr;
            a[m] = *(const short8*)(sA + r * 256 + (kch ^ (r & 7)) * 8);
        }
        #pragma unroll
        for (int n = 0; n < 2; ++n) {
            int r = wc * 32 + n * 16 + fr;
            b[n] = *(const short8*)(sBm + r * 256 + (kch ^ (r & 7)) * 8);
        }
        #pragma unroll
        for (int m = 0; m < 2; ++m)
            #pragma unroll
            for (int n = 0; n < 2; ++n)
                acc[m][n] = __builtin_amdgcn_mfma_f32_16x16x32_bf16(a[m], b[n], acc[m][n], 0, 0, 0);
    }

    #pragma unroll
    for (int m = 0; m < 2; ++m) {
        #pragma unroll
        for (int n = 0; n < 2; ++n) {
            int col = nBase + wc * 32 + n * 16 + fr;
            float bv = bias[col];
            #pragma unroll
            for (int r = 0; r < 4; ++r) {
                int row = rowBase + wr * 32 + m * 16 + kg * 4 + r;
                float v = acc[m][n][r] + bv;
                if (act) v = v > 0.f ? v : 0.01f * v;
                if (outF) outF[(size_t)z * ofZStride + (size_t)row * H_ + col] = v;
                if (outB) outB[(size_t)z * obZStride + (size_t)row * H_ + col] = f2bf(v);
            }
        }
    }
}

// ---------- z = tanh(eps*exp(0.5*lv)+mu) -> bf16 ----------
__global__ void z_kernel(const float* __restrict__ eps, const float* __restrict__ mu,
                         const float* __restrict__ lv, unsigned short* __restrict__ z) {
    int id = blockIdx.x * blockDim.x + threadIdx.x;
    z[id] = f2bf(tanhf(eps[id] * expf(0.5f * lv[id]) + mu[id]));
}

extern "C" void kernel_launch(void* const* d_in, const int* in_sizes, int n_in,
                              void* d_out, int out_size, void* d_ws, size_t ws_size,
                              hipStream_t stream) {
    (void)in_sizes; (void)n_in; (void)out_size; (void)ws_size;
    const float* traj       = (const float*)d_in[0];
    const float* init_s     = (const float*)d_in[1];
    const float* eps        = (const float*)d_in[2];
    const float* enc_emb_W  = (const float*)d_in[3];
    const float* enc_emb_b  = (const float*)d_in[4];
    const float* enc_Wih    = (const float*)d_in[5];
    const float* enc_bih    = (const float*)d_in[6];
    const float* enc_Whh    = (const float*)d_in[7];
    const float* enc_bhh    = (const float*)d_in[8];
    const float* mu_W       = (const float*)d_in[9];
    const float* mu_b       = (const float*)d_in[10];
    const float* lv_W       = (const float*)d_in[11];
    const float* lv_b       = (const float*)d_in[12];
    const float* dec_emb_W  = (const float*)d_in[13];
    const float* dec_emb_b  = (const float*)d_in[14];
    const float* dec_init_W = (const float*)d_in[15];
    const float* dec_init_b = (const float*)d_in[16];
    const float* dec_Wih    = (const float*)d_in[17];
    const float* dec_bih    = (const float*)d_in[18];
    const float* dec_Whh    = (const float*)d_in[19];
    const float* dec_bhh    = (const float*)d_in[20];
    const float* ctrl_W     = (const float*)d_in[21];
    const float* ctrl_b     = (const float*)d_in[22];

    float* out = (float*)d_out;
    float* recons = out;                              // B*T*4
    float* expert = out + (size_t)B_ * T_ * 4;        // B*T*4
    float* mu_out = expert + (size_t)B_ * T_ * 4;     // B*H
    float* lv_out = mu_out + (size_t)B_ * H_;         // B*H

    float* ws = (float*)d_ws;
    size_t o = 0;
    float* rel = ws + o;  o += (size_t)B_ * T_ * 4;
    signed char* WpkE = (signed char*)(ws + o); o += NG_ * H_ / 4;     // int8 image (256KB)
    signed char* WpkD = (signed char*)(ws + o); o += NG_ * H_ / 4;
    unsigned short* WT9  = (unsigned short*)(ws + o); o += 9 * H_ * H_ / 2;
    float* WxPE = ws + o; o += 4 * NG_;
    float* WxPD = ws + o; o += 4 * NG_;
    float* bfPE = ws + o; o += NG_;
    float* bfPD = ws + o; o += NG_;
    unsigned short* hEnc = (unsigned short*)(ws + o); o += (size_t)B_ * H_ / 2;
    unsigned short* tbA  = (unsigned short*)(ws + o); o += (size_t)B_ * H_;  // 2 z-slots
    unsigned short* tbB  = (unsigned short*)(ws + o); o += (size_t)B_ * H_;  // 2 z-slots
    float* cInit = ws + o; o += (size_t)B_ * H_;
    unsigned short* hInit = (unsigned short*)(ws + o); o += (size_t)B_ * H_ / 2;

    hipFuncSetAttribute((const void*)lstm_persist15_kernel<0>,
                        hipFuncAttributeMaxDynamicSharedMemorySize, SMEM15);
    hipFuncSetAttribute((const void*)lstm_persist15_kernel<1>,
                        hipFuncAttributeMaxDynamicSharedMemorySize, SMEM15);

    // ---- prep ----
    fold_perm_kernel<<<80, 256, 0, stream>>>(enc_emb_W, enc_emb_b, enc_Wih, enc_bih, enc_bhh, WxPE, bfPE);
    fold_perm_kernel<<<80, 256, 0, stream>>>(dec_emb_W, dec_emb_b, dec_Wih, dec_bih, dec_bhh, WxPD, bfPD);
    prep_pack_i8_kernel<<<1024, 256, 0, stream>>>(enc_Whh, WpkE);
    prep_pack_i8_kernel<<<1024, 256, 0, stream>>>(dec_Whh, WpkD);
    prep_wt_all_kernel<<<dim3(256, 9), 256, 0, stream>>>(mu_W, lv_W, dec_init_W, WT9);
    rel_kernel<<<(B_ * T_ + 255) / 256, 256, 0, stream>>>(traj, rel, (float4*)expert);

    // ---- encoder (one persistent launch) ----
    lstm_persist15_kernel<0><<<NBLK, 512, SMEM15, stream>>>(
        rel, WpkE, WxPE, bfPE, nullptr, nullptr, nullptr, nullptr, nullptr, hEnc, nullptr);

    // ---- mu/lv MLPs, z-batched ----
    dim3 gridM2(B_ / 64, H_ / 64, 2);
    size_t BH = (size_t)B_ * H_;
    mlp_gemm_kernel<<<gridM2, 256, 0, stream>>>(hEnc, 0, WT9 + 0 * 65536, (size_t)4 * 65536,
                                                mu_b + 0,   lv_b + 0,   nullptr, 0, tbA, BH, 1);
    mlp_gemm_kernel<<<gridM2, 256, 0, stream>>>(tbA, BH, WT9 + 1 * 65536, (size_t)4 * 65536,
                                                mu_b + 256, lv_b + 256, nullptr, 0, tbB, BH, 1);
    mlp_gemm_kernel<<<gridM2, 256, 0, stream>>>(tbB, BH, WT9 + 2 * 65536, (size_t)4 * 65536,
                                                mu_b + 512, lv_b + 512, nullptr, 0, tbA, BH, 1);
    mlp_gemm_kernel<<<gridM2, 256, 0, stream>>>(tbA, BH, WT9 + 3 * 65536, (size_t)4 * 65536,
                                                mu_b + 768, lv_b + 768, mu_out, BH, nullptr, 0, 1);

    // ---- z, decoder init ----
    z_kernel<<<B_ * H_ / 256, 256, 0, stream>>>(eps, mu_out, lv_out, tbB);
    dim3 gridM1(B_ / 64, H_ / 64, 1);
    mlp_gemm_kernel<<<gridM1, 256, 0, stream>>>(tbB, 0, WT9 + 8 * 65536, 0,
                                                dec_init_b, dec_init_b, cInit, 0, hInit, 0, 0);

    // ---- decoder (one persistent launch) ----
    lstm_persist15_kernel<1><<<NBLK, 512, SMEM15, stream>>>(
        nullptr, WpkD, WxPD, bfPD, cInit, hInit, init_s, ctrl_W, ctrl_b, nullptr, recons);
}